// Round 14
// baseline (959.564 us; speedup 1.0000x reference)
//
#include <hip/hip_runtime.h>

#define NN 65536
#define NE 524288
#define BG 512
#define DIN 128
#define HE 256
#define LATD 64
#define HD 512
#define NMX 128
#define NPAIR 8128
#define NST 7
#define CSMAX 2048

// ---------------- CSR build ----------------
__global__ void vae_hist(const int* __restrict__ dst, int* __restrict__ cnt) {
    int e = blockIdx.x * 256 + threadIdx.x;
    if (e < NE) atomicAdd(&cnt[dst[e]], 1);
}

// two-level scan
__global__ void vae_scan1(const int* __restrict__ cnt, int* __restrict__ excl, int* __restrict__ bsum) {
    __shared__ int sd[256];
    const int b = blockIdx.x, t = threadIdx.x;
    int v = cnt[b * 256 + t];
    sd[t] = v;
    __syncthreads();
    int acc = v;
    for (int off = 1; off < 256; off <<= 1) {
        int tv = (t >= off) ? sd[t - off] : 0;
        __syncthreads();
        acc += tv;
        sd[t] = acc;
        __syncthreads();
    }
    excl[b * 256 + t] = acc - v;
    if (t == 255) bsum[b] = acc;
}

__global__ void vae_scan2(int* __restrict__ bsum) {
    __shared__ int sd[256];
    const int t = threadIdx.x;
    int v = bsum[t];
    sd[t] = v;
    __syncthreads();
    int acc = v;
    for (int off = 1; off < 256; off <<= 1) {
        int tv = (t >= off) ? sd[t - off] : 0;
        __syncthreads();
        acc += tv;
        sd[t] = acc;
        __syncthreads();
    }
    bsum[t] = acc - v;  // exclusive
}

__global__ void vae_scan3(const int* __restrict__ excl, const int* __restrict__ bsum,
                          int* __restrict__ rs, int* __restrict__ cur) {
    const int i = blockIdx.x * 256 + threadIdx.x;
    const int v = excl[i] + bsum[blockIdx.x];
    rs[i] = v;
    cur[i] = v;
    if (i == NN - 1) rs[NN] = NE;
}

__global__ void vae_fill(const int* __restrict__ dst, int* __restrict__ cur, int* __restrict__ eid) {
    int e = blockIdx.x * 256 + threadIdx.x;
    if (e < NE) {
        int p = atomicAdd(&cur[dst[e]], 1);
        eid[p] = e;
    }
}

// canonicalize order (deterministic)
__global__ void vae_sort(const int* __restrict__ rs, int* __restrict__ eid,
                         const int* __restrict__ srcarr, int* __restrict__ csrc) {
    int n = blockIdx.x * 256 + threadIdx.x;
    if (n >= NN) return;
    int s = rs[n], e = rs[n + 1];
    for (int a = s + 1; a < e; ++a) {
        int key = eid[a];
        int b = a - 1;
        while (b >= s && eid[b] > key) { eid[b + 1] = eid[b]; --b; }
        eid[b + 1] = key;
    }
    for (int a = s; a < e; ++a) csrc[a] = srcarr[eid[a]];
}

// ---------------- fused agg + GEMM1: T = bn(lrelu((h + gather) @ W1 + b1)) -------------------
// 128x256 / BK=32 proven structure; A-staging gathers h[row] + sum h[csrc[a]].
// csrc slice for the block's 128 rows is staged in LDS ONCE (contiguous range; guarded
// fallback past CSMAX) -> no 8x global index re-reads, shorter per-edge dep chain.
// Gather: 5-edge load batches (+2/+1 tails), accumulated strictly IN EDGE ORDER into a
// single chain — bitwise-identical to the sequential CSR walk. NUMERICS RULE (round-10
// failure): the edge-sum ORDER is load-bearing; never reorder the adds.
template <int K>
__global__ __launch_bounds__(256, 2) void vae_gemm1f(const float* __restrict__ Hm,
                                                     const int* __restrict__ rs,
                                                     const int* __restrict__ csrc,
                                                     const float* __restrict__ W,
                                                     const float* __restrict__ bias,
                                                     const float* __restrict__ g,
                                                     const float* __restrict__ be,
                                                     float* __restrict__ Out) {
    __shared__ float As[32][132];
    __shared__ float Bs[32][264];
    __shared__ int cs[CSMAX];
    const int tid = threadIdx.x;
    const int tx = tid & 15, ty = tid >> 4;
    const int rowBlk = blockIdx.x * 128;

    float acc[8][16];
#pragma unroll
    for (int r = 0; r < 8; r++)
#pragma unroll
        for (int c = 0; c < 16; c++) acc[r][c] = 0.f;

    const int arow = tid >> 1;       // 0..127
    const int ak = (tid & 1) * 16;   // 0 or 16
    const int row = rowBlk + arow;
    const int s0 = rs[row], e0 = rs[row + 1];
    const float* aown = Hm + (size_t)row * K + ak;
    const float* bptr = W + (size_t)ty * HE + tx * 4;  // stages k-rows ty and ty+16

    // stage this block's csrc slice (contiguous: rows rowBlk..rowBlk+127)
    const int sBlk = rs[rowBlk];
    const int eBlk = rs[rowBlk + 128];
    const int nE = eBlk - sBlk;
    for (int i = tid; i < nE && i < CSMAX; i += 256) cs[i] = csrc[sBlk + i];
    __syncthreads();

    auto cidx = [&](int a) -> int {
        int i = a - sBlk;
        return (i < CSMAX) ? cs[i] : csrc[a];
    };

    float4 pa0, pa1, pa2, pa3;
    float4 pb0, pb1, pb2, pb3, pb4, pb5, pb6, pb7;
    auto gload = [&](int ck) {
        const size_t off = (size_t)ak + (size_t)ck * 32;
        const float* an = aown + ck * 32;
        pa0 = *reinterpret_cast<const float4*>(an);
        pa1 = *reinterpret_cast<const float4*>(an + 4);
        pa2 = *reinterpret_cast<const float4*>(an + 8);
        pa3 = *reinterpret_cast<const float4*>(an + 12);
        int a = s0;
        // 5-edge load batches; IN-ORDER single-chain accumulation (matches reference).
        while (a + 4 < e0) {
            const float* p0 = Hm + (size_t)cidx(a) * K + off;
            const float* p1 = Hm + (size_t)cidx(a + 1) * K + off;
            const float* p2 = Hm + (size_t)cidx(a + 2) * K + off;
            const float* p3 = Hm + (size_t)cidx(a + 3) * K + off;
            const float* p4 = Hm + (size_t)cidx(a + 4) * K + off;
            float4 n0 = *reinterpret_cast<const float4*>(p0);
            float4 n1 = *reinterpret_cast<const float4*>(p0 + 4);
            float4 n2 = *reinterpret_cast<const float4*>(p0 + 8);
            float4 n3 = *reinterpret_cast<const float4*>(p0 + 12);
            float4 m0 = *reinterpret_cast<const float4*>(p1);
            float4 m1 = *reinterpret_cast<const float4*>(p1 + 4);
            float4 m2 = *reinterpret_cast<const float4*>(p1 + 8);
            float4 m3 = *reinterpret_cast<const float4*>(p1 + 12);
            float4 u0 = *reinterpret_cast<const float4*>(p2);
            float4 u1 = *reinterpret_cast<const float4*>(p2 + 4);
            float4 u2 = *reinterpret_cast<const float4*>(p2 + 8);
            float4 u3 = *reinterpret_cast<const float4*>(p2 + 12);
            float4 v0 = *reinterpret_cast<const float4*>(p3);
            float4 v1 = *reinterpret_cast<const float4*>(p3 + 4);
            float4 v2 = *reinterpret_cast<const float4*>(p3 + 8);
            float4 v3 = *reinterpret_cast<const float4*>(p3 + 12);
            float4 w0 = *reinterpret_cast<const float4*>(p4);
            float4 w1 = *reinterpret_cast<const float4*>(p4 + 4);
            float4 w2 = *reinterpret_cast<const float4*>(p4 + 8);
            float4 w3 = *reinterpret_cast<const float4*>(p4 + 12);
            // edge a
            pa0.x += n0.x; pa0.y += n0.y; pa0.z += n0.z; pa0.w += n0.w;
            pa1.x += n1.x; pa1.y += n1.y; pa1.z += n1.z; pa1.w += n1.w;
            pa2.x += n2.x; pa2.y += n2.y; pa2.z += n2.z; pa2.w += n2.w;
            pa3.x += n3.x; pa3.y += n3.y; pa3.z += n3.z; pa3.w += n3.w;
            // edge a+1
            pa0.x += m0.x; pa0.y += m0.y; pa0.z += m0.z; pa0.w += m0.w;
            pa1.x += m1.x; pa1.y += m1.y; pa1.z += m1.z; pa1.w += m1.w;
            pa2.x += m2.x; pa2.y += m2.y; pa2.z += m2.z; pa2.w += m2.w;
            pa3.x += m3.x; pa3.y += m3.y; pa3.z += m3.z; pa3.w += m3.w;
            // edge a+2
            pa0.x += u0.x; pa0.y += u0.y; pa0.z += u0.z; pa0.w += u0.w;
            pa1.x += u1.x; pa1.y += u1.y; pa1.z += u1.z; pa1.w += u1.w;
            pa2.x += u2.x; pa2.y += u2.y; pa2.z += u2.z; pa2.w += u2.w;
            pa3.x += u3.x; pa3.y += u3.y; pa3.z += u3.z; pa3.w += u3.w;
            // edge a+3
            pa0.x += v0.x; pa0.y += v0.y; pa0.z += v0.z; pa0.w += v0.w;
            pa1.x += v1.x; pa1.y += v1.y; pa1.z += v1.z; pa1.w += v1.w;
            pa2.x += v2.x; pa2.y += v2.y; pa2.z += v2.z; pa2.w += v2.w;
            pa3.x += v3.x; pa3.y += v3.y; pa3.z += v3.z; pa3.w += v3.w;
            // edge a+4
            pa0.x += w0.x; pa0.y += w0.y; pa0.z += w0.z; pa0.w += w0.w;
            pa1.x += w1.x; pa1.y += w1.y; pa1.z += w1.z; pa1.w += w1.w;
            pa2.x += w2.x; pa2.y += w2.y; pa2.z += w2.z; pa2.w += w2.w;
            pa3.x += w3.x; pa3.y += w3.y; pa3.z += w3.z; pa3.w += w3.w;
            a += 5;
        }
        // 2-edge tail batches
        while (a + 1 < e0) {
            const float* p0 = Hm + (size_t)cidx(a) * K + off;
            const float* p1 = Hm + (size_t)cidx(a + 1) * K + off;
            float4 n0 = *reinterpret_cast<const float4*>(p0);
            float4 n1 = *reinterpret_cast<const float4*>(p0 + 4);
            float4 n2 = *reinterpret_cast<const float4*>(p0 + 8);
            float4 n3 = *reinterpret_cast<const float4*>(p0 + 12);
            float4 m0 = *reinterpret_cast<const float4*>(p1);
            float4 m1 = *reinterpret_cast<const float4*>(p1 + 4);
            float4 m2 = *reinterpret_cast<const float4*>(p1 + 8);
            float4 m3 = *reinterpret_cast<const float4*>(p1 + 12);
            pa0.x += n0.x; pa0.y += n0.y; pa0.z += n0.z; pa0.w += n0.w;
            pa1.x += n1.x; pa1.y += n1.y; pa1.z += n1.z; pa1.w += n1.w;
            pa2.x += n2.x; pa2.y += n2.y; pa2.z += n2.z; pa2.w += n2.w;
            pa3.x += n3.x; pa3.y += n3.y; pa3.z += n3.z; pa3.w += n3.w;
            pa0.x += m0.x; pa0.y += m0.y; pa0.z += m0.z; pa0.w += m0.w;
            pa1.x += m1.x; pa1.y += m1.y; pa1.z += m1.z; pa1.w += m1.w;
            pa2.x += m2.x; pa2.y += m2.y; pa2.z += m2.z; pa2.w += m2.w;
            pa3.x += m3.x; pa3.y += m3.y; pa3.z += m3.z; pa3.w += m3.w;
            a += 2;
        }
        if (a < e0) {
            const float* p0 = Hm + (size_t)cidx(a) * K + off;
            float4 n0 = *reinterpret_cast<const float4*>(p0);
            float4 n1 = *reinterpret_cast<const float4*>(p0 + 4);
            float4 n2 = *reinterpret_cast<const float4*>(p0 + 8);
            float4 n3 = *reinterpret_cast<const float4*>(p0 + 12);
            pa0.x += n0.x; pa0.y += n0.y; pa0.z += n0.z; pa0.w += n0.w;
            pa1.x += n1.x; pa1.y += n1.y; pa1.z += n1.z; pa1.w += n1.w;
            pa2.x += n2.x; pa2.y += n2.y; pa2.z += n2.z; pa2.w += n2.w;
            pa3.x += n3.x; pa3.y += n3.y; pa3.z += n3.z; pa3.w += n3.w;
        }
        // B-panel loads last: consumed at next swrite, covered by the FMA loop.
        const float* bn0 = bptr + (size_t)(ck * 32) * HE;
        pb0 = *reinterpret_cast<const float4*>(bn0);
        pb1 = *reinterpret_cast<const float4*>(bn0 + 64);
        pb2 = *reinterpret_cast<const float4*>(bn0 + 128);
        pb3 = *reinterpret_cast<const float4*>(bn0 + 192);
        const float* bn1 = bn0 + 16 * HE;
        pb4 = *reinterpret_cast<const float4*>(bn1);
        pb5 = *reinterpret_cast<const float4*>(bn1 + 64);
        pb6 = *reinterpret_cast<const float4*>(bn1 + 128);
        pb7 = *reinterpret_cast<const float4*>(bn1 + 192);
    };
    auto swrite = [&]() {
        As[ak + 0][arow] = pa0.x;  As[ak + 1][arow] = pa0.y;
        As[ak + 2][arow] = pa0.z;  As[ak + 3][arow] = pa0.w;
        As[ak + 4][arow] = pa1.x;  As[ak + 5][arow] = pa1.y;
        As[ak + 6][arow] = pa1.z;  As[ak + 7][arow] = pa1.w;
        As[ak + 8][arow] = pa2.x;  As[ak + 9][arow] = pa2.y;
        As[ak + 10][arow] = pa2.z; As[ak + 11][arow] = pa2.w;
        As[ak + 12][arow] = pa3.x; As[ak + 13][arow] = pa3.y;
        As[ak + 14][arow] = pa3.z; As[ak + 15][arow] = pa3.w;
        *reinterpret_cast<float4*>(&Bs[ty][tx * 4]) = pb0;
        *reinterpret_cast<float4*>(&Bs[ty][tx * 4 + 64]) = pb1;
        *reinterpret_cast<float4*>(&Bs[ty][tx * 4 + 128]) = pb2;
        *reinterpret_cast<float4*>(&Bs[ty][tx * 4 + 192]) = pb3;
        *reinterpret_cast<float4*>(&Bs[ty + 16][tx * 4]) = pb4;
        *reinterpret_cast<float4*>(&Bs[ty + 16][tx * 4 + 64]) = pb5;
        *reinterpret_cast<float4*>(&Bs[ty + 16][tx * 4 + 128]) = pb6;
        *reinterpret_cast<float4*>(&Bs[ty + 16][tx * 4 + 192]) = pb7;
    };

    constexpr int NCK = K / 32;
    gload(0);
    for (int ck = 0; ck < NCK; ++ck) {
        __syncthreads();
        swrite();
        __syncthreads();
        if (ck + 1 < NCK) gload(ck + 1);
#pragma unroll 16
        for (int k = 0; k < 32; ++k) {
            float4 a0 = *reinterpret_cast<const float4*>(&As[k][ty * 8]);
            float4 a1 = *reinterpret_cast<const float4*>(&As[k][ty * 8 + 4]);
            float4 b0 = *reinterpret_cast<const float4*>(&Bs[k][tx * 4]);
            float4 b1 = *reinterpret_cast<const float4*>(&Bs[k][tx * 4 + 64]);
            float4 b2 = *reinterpret_cast<const float4*>(&Bs[k][tx * 4 + 128]);
            float4 b3 = *reinterpret_cast<const float4*>(&Bs[k][tx * 4 + 192]);
            float ar[8] = {a0.x, a0.y, a0.z, a0.w, a1.x, a1.y, a1.z, a1.w};
            float bv[16] = {b0.x, b0.y, b0.z, b0.w, b1.x, b1.y, b1.z, b1.w,
                            b2.x, b2.y, b2.z, b2.w, b3.x, b3.y, b3.z, b3.w};
#pragma unroll
            for (int r = 0; r < 8; r++)
#pragma unroll
                for (int c = 0; c < 16; c++)
                    acc[r][c] = fmaf(ar[r], bv[c], acc[r][c]);
        }
    }

    const float sq = sqrtf(1.0f + 1e-5f);
#pragma unroll
    for (int cg = 0; cg < 4; cg++) {
        const int col = cg * 64 + tx * 4;
        float4 bb = *reinterpret_cast<const float4*>(&bias[col]);
        float4 gg = *reinterpret_cast<const float4*>(&g[col]);
        float4 ee = *reinterpret_cast<const float4*>(&be[col]);
        float bbv[4] = {bb.x, bb.y, bb.z, bb.w};
        float sc[4] = {gg.x / sq, gg.y / sq, gg.z / sq, gg.w / sq};
        float bev[4] = {ee.x, ee.y, ee.z, ee.w};
#pragma unroll
        for (int r = 0; r < 8; r++) {
            const int orow = rowBlk + ty * 8 + r;
            float o[4];
#pragma unroll
            for (int c = 0; c < 4; c++) {
                float t = acc[r][cg * 4 + c] + bbv[c];
                t = t > 0.f ? t : 0.2f * t;
                o[c] = t * sc[c] + bev[c];
            }
            *reinterpret_cast<float4*>(Out + (size_t)orow * HE + col) =
                *reinterpret_cast<float4*>(&o[0]);
        }
    }
}

// ---------------- LDS-staged SGEMM (gemm2), 128x256, BK=32, proven operating point -----------
// EPI 1: lrelu(.) -> Out; EPI 2: lrelu(.) -> per-graph pooled column sums (NO h store)
template <int K, int EPI>
__global__ __launch_bounds__(256, 2) void vae_sgemm(const float* __restrict__ A,
                                                    const float* __restrict__ W,
                                                    const float* __restrict__ bias,
                                                    float* __restrict__ Out) {
    __shared__ float As[32][132];
    __shared__ float Bs[32][264];
    const int tid = threadIdx.x;
    const int tx = tid & 15, ty = tid >> 4;
    const int rowBlk = blockIdx.x * 128;

    float acc[8][16];
#pragma unroll
    for (int r = 0; r < 8; r++)
#pragma unroll
        for (int c = 0; c < 16; c++) acc[r][c] = 0.f;

    const int arow = tid >> 1;       // 0..127
    const int ak = (tid & 1) * 16;   // 0 or 16
    const float* aptr = A + (size_t)(rowBlk + arow) * K + ak;
    const float* bptr = W + (size_t)ty * HE + tx * 4;  // stages k-rows ty and ty+16

    float4 pa0, pa1, pa2, pa3;
    float4 pb0, pb1, pb2, pb3, pb4, pb5, pb6, pb7;
    auto gload = [&](int ck) {
        const float* an = aptr + ck * 32;
        pa0 = *reinterpret_cast<const float4*>(an);
        pa1 = *reinterpret_cast<const float4*>(an + 4);
        pa2 = *reinterpret_cast<const float4*>(an + 8);
        pa3 = *reinterpret_cast<const float4*>(an + 12);
        const float* bn0 = bptr + (size_t)(ck * 32) * HE;
        pb0 = *reinterpret_cast<const float4*>(bn0);
        pb1 = *reinterpret_cast<const float4*>(bn0 + 64);
        pb2 = *reinterpret_cast<const float4*>(bn0 + 128);
        pb3 = *reinterpret_cast<const float4*>(bn0 + 192);
        const float* bn1 = bn0 + 16 * HE;
        pb4 = *reinterpret_cast<const float4*>(bn1);
        pb5 = *reinterpret_cast<const float4*>(bn1 + 64);
        pb6 = *reinterpret_cast<const float4*>(bn1 + 128);
        pb7 = *reinterpret_cast<const float4*>(bn1 + 192);
    };
    auto swrite = [&]() {
        As[ak + 0][arow] = pa0.x;  As[ak + 1][arow] = pa0.y;
        As[ak + 2][arow] = pa0.z;  As[ak + 3][arow] = pa0.w;
        As[ak + 4][arow] = pa1.x;  As[ak + 5][arow] = pa1.y;
        As[ak + 6][arow] = pa1.z;  As[ak + 7][arow] = pa1.w;
        As[ak + 8][arow] = pa2.x;  As[ak + 9][arow] = pa2.y;
        As[ak + 10][arow] = pa2.z; As[ak + 11][arow] = pa2.w;
        As[ak + 12][arow] = pa3.x; As[ak + 13][arow] = pa3.y;
        As[ak + 14][arow] = pa3.z; As[ak + 15][arow] = pa3.w;
        *reinterpret_cast<float4*>(&Bs[ty][tx * 4]) = pb0;
        *reinterpret_cast<float4*>(&Bs[ty][tx * 4 + 64]) = pb1;
        *reinterpret_cast<float4*>(&Bs[ty][tx * 4 + 128]) = pb2;
        *reinterpret_cast<float4*>(&Bs[ty][tx * 4 + 192]) = pb3;
        *reinterpret_cast<float4*>(&Bs[ty + 16][tx * 4]) = pb4;
        *reinterpret_cast<float4*>(&Bs[ty + 16][tx * 4 + 64]) = pb5;
        *reinterpret_cast<float4*>(&Bs[ty + 16][tx * 4 + 128]) = pb6;
        *reinterpret_cast<float4*>(&Bs[ty + 16][tx * 4 + 192]) = pb7;
    };

    constexpr int NCK = K / 32;
    gload(0);
    for (int ck = 0; ck < NCK; ++ck) {
        __syncthreads();
        swrite();
        __syncthreads();
        if (ck + 1 < NCK) gload(ck + 1);
#pragma unroll 16
        for (int k = 0; k < 32; ++k) {
            float4 a0 = *reinterpret_cast<const float4*>(&As[k][ty * 8]);
            float4 a1 = *reinterpret_cast<const float4*>(&As[k][ty * 8 + 4]);
            float4 b0 = *reinterpret_cast<const float4*>(&Bs[k][tx * 4]);
            float4 b1 = *reinterpret_cast<const float4*>(&Bs[k][tx * 4 + 64]);
            float4 b2 = *reinterpret_cast<const float4*>(&Bs[k][tx * 4 + 128]);
            float4 b3 = *reinterpret_cast<const float4*>(&Bs[k][tx * 4 + 192]);
            float ar[8] = {a0.x, a0.y, a0.z, a0.w, a1.x, a1.y, a1.z, a1.w};
            float bv[16] = {b0.x, b0.y, b0.z, b0.w, b1.x, b1.y, b1.z, b1.w,
                            b2.x, b2.y, b2.z, b2.w, b3.x, b3.y, b3.z, b3.w};
#pragma unroll
            for (int r = 0; r < 8; r++)
#pragma unroll
                for (int c = 0; c < 16; c++)
                    acc[r][c] = fmaf(ar[r], bv[c], acc[r][c]);
        }
    }

    if constexpr (EPI == 2) {
        float psum[16];
#pragma unroll
        for (int c = 0; c < 16; c++) psum[c] = 0.f;
#pragma unroll
        for (int cg = 0; cg < 4; cg++) {
            const int col = cg * 64 + tx * 4;
            float4 bb = *reinterpret_cast<const float4*>(&bias[col]);
            float bbv[4] = {bb.x, bb.y, bb.z, bb.w};
#pragma unroll
            for (int r = 0; r < 8; r++)
#pragma unroll
                for (int c = 0; c < 4; c++) {
                    float t = acc[r][cg * 4 + c] + bbv[c];
                    t = t > 0.f ? t : 0.2f * t;
                    psum[cg * 4 + c] += t;
                }
        }
        __syncthreads();
#pragma unroll
        for (int cg = 0; cg < 4; cg++)
#pragma unroll
            for (int c = 0; c < 4; c++)
                Bs[ty][cg * 64 + tx * 4 + c] = psum[cg * 4 + c];
        __syncthreads();
        float s = 0.f;
#pragma unroll
        for (int k = 0; k < 16; k++) s += Bs[k][tid];
        Out[(size_t)blockIdx.x * HE + tid] = s;  // pooled[graph][col]
        return;
    }

#pragma unroll
    for (int cg = 0; cg < 4; cg++) {
        const int col = cg * 64 + tx * 4;
        float4 bb = *reinterpret_cast<const float4*>(&bias[col]);
        float bbv[4] = {bb.x, bb.y, bb.z, bb.w};
#pragma unroll
        for (int r = 0; r < 8; r++) {
            const int row = rowBlk + ty * 8 + r;
            float o[4];
#pragma unroll
            for (int c = 0; c < 4; c++) {
                float t = acc[r][cg * 4 + c] + bbv[c];
                o[c] = t > 0.f ? t : 0.2f * t;
            }
            *reinterpret_cast<float4*>(Out + (size_t)row * HE + col) =
                *reinterpret_cast<float4*>(&o[0]);
        }
    }
}

// ---------------- pooled(precomputed) -> bn -> fc -> mu -> d0 -> d1, one block per graph ----
__global__ __launch_bounds__(256) void vae_pooldec(const float* __restrict__ pooled, const float* __restrict__ stats,
                                                   const float* __restrict__ bng, const float* __restrict__ bnb,
                                                   const float* __restrict__ fcw, const float* __restrict__ fcb,
                                                   const float* __restrict__ muw, const float* __restrict__ mub,
                                                   const float* __restrict__ d0w, const float* __restrict__ d0b,
                                                   const float* __restrict__ d1w, const float* __restrict__ d1b,
                                                   float* __restrict__ Dm) {
    __shared__ float vin[264];
    __shared__ float fo[256];
    __shared__ float z[72];
    __shared__ float dd[512];
    const int b = blockIdx.x, t = threadIdx.x;

    const float sq = sqrtf(1.0f + 1e-5f);
    float m0 = pooled[(size_t)b * HE + t] * (bng[t] / sq) + bnb[t];
    vin[t] = m0;
    if (t < NST) vin[HE + t] = stats[b * NST + t] * (bng[HE + t] / sq) + bnb[HE + t];
    __syncthreads();

    float a = fcb[t];
    for (int k = 0; k < HE + NST; k++) a = fmaf(vin[k], fcw[(size_t)k * HE + t], a);
    fo[t] = a;
    __syncthreads();

    if (t < LATD) {
        float m = mub[t];
        for (int k = 0; k < HE; k++) m = fmaf(fo[k], muw[(size_t)k * LATD + t], m);
        z[t] = m;
    }
    if (t >= LATD && t < LATD + NST) z[t] = stats[b * NST + (t - LATD)];
    __syncthreads();

    float a0 = d0b[t], a1 = d0b[t + 256];
    for (int k = 0; k < LATD + NST; k++) {
        float zk = z[k];
        a0 = fmaf(zk, d0w[(size_t)k * HD + t], a0);
        a1 = fmaf(zk, d0w[(size_t)k * HD + t + 256], a1);
    }
    dd[t] = a0 > 0.f ? a0 : 0.f;
    dd[t + 256] = a1 > 0.f ? a1 : 0.f;
    __syncthreads();

    float c0 = d1b[t], c1 = d1b[t + 256];
    for (int k = 0; k < HD; k++) {
        float dk = dd[k];
        c0 = fmaf(dk, d1w[(size_t)k * HD + t], c0);
        c1 = fmaf(dk, d1w[(size_t)k * HD + t + 256], c1);
    }
    Dm[(size_t)b * HD + t] = c0 > 0.f ? c0 : 0.f;
    Dm[(size_t)b * HD + t + 256] = c1 > 0.f ? c1 : 0.f;
}

// ---------------- d2 difference-GEMM, 128 rows x 64 cols, grid (128,4)=512 blocks ------------
// B-staging reads RAW d2w pairs and diffs inline; epilogue reads gum directly and writes vals.
__global__ __launch_bounds__(256, 4) void vae_d2gemm(const float* __restrict__ A,    // Dm 512x512
                                                     const float* __restrict__ Wraw, // d2w 512x16256
                                                     const float* __restrict__ Bb,   // d2b 16256
                                                     const float* __restrict__ gum,  // 512x16256
                                                     float* __restrict__ Vals) {     // 512x8192
    __shared__ float As[16][132];
    __shared__ float Bs[16][68];
    const int tid = threadIdx.x;
    const int tx = tid & 15, ty = tid >> 4;
    const int rowBlk = blockIdx.y * 128, colBlk = blockIdx.x * 64;

    float acc[8][4];
#pragma unroll
    for (int r = 0; r < 8; r++)
#pragma unroll
        for (int c = 0; c < 4; c++) acc[r][c] = 0.f;

    const int arow = tid >> 1;
    const int ak = (tid & 1) * 8;
    const float* aptr = A + (size_t)(rowBlk + arow) * HD + ak;
    const int bk = tid >> 4;        // 0..15 (k row within chunk)
    const int bc = (tid & 15) * 4;  // 0..60 (pair group)
    const int p0 = colBlk + bc;     // pair index, multiple of 4
    const bool pvalid = (p0 < NPAIR);  // NPAIR % 4 == 0, so all 4 pairs valid together
    const float* wrow = Wraw + (size_t)bk * (2 * NPAIR) + 2 * p0;

    float4 pa0 = *reinterpret_cast<const float4*>(aptr);
    float4 pa1 = *reinterpret_cast<const float4*>(aptr + 4);
    float4 pu = {0.f, 0.f, 0.f, 0.f}, pv = {0.f, 0.f, 0.f, 0.f};
    if (pvalid) {
        pu = *reinterpret_cast<const float4*>(wrow);
        pv = *reinterpret_cast<const float4*>(wrow + 4);
    }

    constexpr int NCK = HD / 16;
    for (int ck = 0; ck < NCK; ++ck) {
        __syncthreads();
        As[ak + 0][arow] = pa0.x;
        As[ak + 1][arow] = pa0.y;
        As[ak + 2][arow] = pa0.z;
        As[ak + 3][arow] = pa0.w;
        As[ak + 4][arow] = pa1.x;
        As[ak + 5][arow] = pa1.y;
        As[ak + 6][arow] = pa1.z;
        As[ak + 7][arow] = pa1.w;
        {
            float4 d;
            d.x = pu.x - pu.y; d.y = pu.z - pu.w;
            d.z = pv.x - pv.y; d.w = pv.z - pv.w;
            *reinterpret_cast<float4*>(&Bs[bk][bc]) = d;
        }
        __syncthreads();
        if (ck + 1 < NCK) {
            const float* an = aptr + (ck + 1) * 16;
            pa0 = *reinterpret_cast<const float4*>(an);
            pa1 = *reinterpret_cast<const float4*>(an + 4);
            if (pvalid) {
                const float* wn = wrow + (size_t)(ck + 1) * 16 * (2 * NPAIR);
                pu = *reinterpret_cast<const float4*>(wn);
                pv = *reinterpret_cast<const float4*>(wn + 4);
            }
        }
#pragma unroll
        for (int k = 0; k < 16; ++k) {
            float4 a0 = *reinterpret_cast<const float4*>(&As[k][ty * 8]);
            float4 a1 = *reinterpret_cast<const float4*>(&As[k][ty * 8 + 4]);
            float4 b = *reinterpret_cast<const float4*>(&Bs[k][tx * 4]);
            float ar[8] = {a0.x, a0.y, a0.z, a0.w, a1.x, a1.y, a1.z, a1.w};
            float bv[4] = {b.x, b.y, b.z, b.w};
#pragma unroll
            for (int r = 0; r < 8; r++)
#pragma unroll
                for (int c = 0; c < 4; c++)
                    acc[r][c] = fmaf(ar[r], bv[c], acc[r][c]);
        }
    }

    if (pvalid) {
        const float* bp = Bb + 2 * p0;
        float4 u = *reinterpret_cast<const float4*>(bp);
        float4 v = *reinterpret_cast<const float4*>(bp + 4);
        float bd[4] = {u.x - u.y, u.z - u.w, v.x - v.y, v.z - v.w};
#pragma unroll
        for (int r = 0; r < 8; r++) {
            const int b_ = rowBlk + ty * 8 + r;
            const float* gp = gum + (size_t)b_ * (2 * NPAIR) + 2 * p0;
            float4 gu = *reinterpret_cast<const float4*>(gp);
            float4 gv = *reinterpret_cast<const float4*>(gp + 4);
            float gd[4] = {gu.x - gu.y, gu.z - gu.w, gv.x - gv.y, gv.z - gv.w};
            float o[4];
#pragma unroll
            for (int c = 0; c < 4; c++) {
                float y = acc[r][c] + bd[c] + gd[c];
                o[c] = (y >= 0.f) ? 1.0f : 0.0f;
            }
            *reinterpret_cast<float4*>(Vals + (size_t)b_ * 8192 + p0) =
                *reinterpret_cast<float4*>(&o[0]);
        }
    }
}

// ---------------- scatter: vals -> symmetric adjacency, one block per graph ----------------
__global__ __launch_bounds__(256) void vae_scatter(const float* __restrict__ vals, float* __restrict__ Out) {
    __shared__ float sv[8192];
    const int b = blockIdx.x, t = threadIdx.x;
    const float* vp = vals + (size_t)b * 8192;
#pragma unroll
    for (int i = 0; i < 8; ++i)
        *reinterpret_cast<float4*>(&sv[(i * 256 + t) * 4]) =
            *reinterpret_cast<const float4*>(&vp[(i * 256 + t) * 4]);
    __syncthreads();
    float* op = Out + (size_t)b * (NMX * NMX);
#pragma unroll
    for (int it = 0; it < 16; ++it) {
        int pos = (it * 256 + t) * 4;
        int i = pos >> 7, j0 = pos & 127;
        float o[4];
#pragma unroll
        for (int e = 0; e < 4; ++e) {
            int j = j0 + e;
            float v;
            if (i == j) v = 0.f;
            else if (i < j) v = sv[((i * (255 - i)) >> 1) + j - i - 1];
            else v = sv[((j * (255 - j)) >> 1) + i - j - 1];
            o[e] = v;
        }
        *reinterpret_cast<float4*>(&op[pos]) = *reinterpret_cast<float4*>(&o[0]);
    }
}

extern "C" void kernel_launch(void* const* d_in, const int* in_sizes, int n_in,
                              void* d_out, int out_size, void* d_ws, size_t ws_size,
                              hipStream_t stream) {
    const float* x = (const float*)d_in[0];
    const int* ei = (const int*)d_in[1];  // [0..NE) = src, [NE..2NE) = dst
    const float* stats = (const float*)d_in[3];
    const float* gum = (const float*)d_in[4];
    const float* cw1[3] = {(const float*)d_in[5], (const float*)d_in[11], (const float*)d_in[17]};
    const float* cb1[3] = {(const float*)d_in[6], (const float*)d_in[12], (const float*)d_in[18]};
    const float* cg[3] = {(const float*)d_in[7], (const float*)d_in[13], (const float*)d_in[19]};
    const float* cbe[3] = {(const float*)d_in[8], (const float*)d_in[14], (const float*)d_in[20]};
    const float* cw2[3] = {(const float*)d_in[9], (const float*)d_in[15], (const float*)d_in[21]};
    const float* cb2[3] = {(const float*)d_in[10], (const float*)d_in[16], (const float*)d_in[22]};
    const float* bng = (const float*)d_in[23];
    const float* bnb = (const float*)d_in[24];
    const float* fcw = (const float*)d_in[25];
    const float* fcb = (const float*)d_in[26];
    const float* muw = (const float*)d_in[27];
    const float* mub = (const float*)d_in[28];
    const float* d0w = (const float*)d_in[29];
    const float* d0b = (const float*)d_in[30];
    const float* d1w = (const float*)d_in[31];
    const float* d1b = (const float*)d_in[32];
    const float* d2w = (const float*)d_in[33];
    const float* d2b = (const float*)d_in[34];
    float* Out = (float*)d_out;

    char* wp = (char*)d_ws;
    auto alloc = [&](size_t bytes) -> void* {
        void* p = (void*)wp;
        wp += (bytes + 255) & ~(size_t)255;
        return p;
    };
    float* hA = (float*)alloc((size_t)NN * HE * 4);
    float* hB = (float*)alloc((size_t)NN * HE * 4);
    int* cnt = (int*)alloc((size_t)NN * 4);
    int* rs = (int*)alloc((size_t)(NN + 64) * 4);
    int* cur = (int*)alloc((size_t)NN * 4);
    int* eid = (int*)alloc((size_t)NE * 4);
    int* csrc = (int*)alloc((size_t)NE * 4);
    int* bsum = (int*)alloc((size_t)256 * 4);
    float* Dm = (float*)alloc((size_t)BG * HD * 4);
    float* pooled = (float*)alloc((size_t)BG * HE * 4);

    // vals aliases hA: hA is dead after the last gemm2 reads it, and the d2 chain
    // launches after that point (stream-ordered).
    float* vals = hA;  // 512 x 8192

    const int* srcArr = ei;
    const int* dstArr = ei + NE;

    hipMemsetAsync(cnt, 0, (size_t)NN * 4, stream);
    vae_hist<<<NE / 256, 256, 0, stream>>>(dstArr, cnt);
    vae_scan1<<<NN / 256, 256, 0, stream>>>(cnt, cur, bsum);
    vae_scan2<<<1, 256, 0, stream>>>(bsum);
    vae_scan3<<<NN / 256, 256, 0, stream>>>(cur, bsum, rs, cur);
    vae_fill<<<NE / 256, 256, 0, stream>>>(dstArr, cur, eid);
    vae_sort<<<NN / 256, 256, 0, stream>>>(rs, eid, srcArr, csrc);

    // layer 0: fused agg+gemm1: x -> hA(T); gemm2: hA -> hB(h1)
    vae_gemm1f<DIN><<<NN / 128, 256, 0, stream>>>(x, rs, csrc, cw1[0], cb1[0], cg[0], cbe[0], hA);
    vae_sgemm<HE, 1><<<NN / 128, 256, 0, stream>>>(hA, cw2[0], cb2[0], hB);
    // layer 1
    vae_gemm1f<HE><<<NN / 128, 256, 0, stream>>>(hB, rs, csrc, cw1[1], cb1[1], cg[1], cbe[1], hA);
    vae_sgemm<HE, 1><<<NN / 128, 256, 0, stream>>>(hA, cw2[1], cb2[1], hB);
    // layer 2: fused agg+gemm1: hB -> hA(T3); gemm2(EPI=2): hA -> pooled (no h store)
    vae_gemm1f<HE><<<NN / 128, 256, 0, stream>>>(hB, rs, csrc, cw1[2], cb1[2], cg[2], cbe[2], hA);
    vae_sgemm<HE, 2><<<NN / 128, 256, 0, stream>>>(hA, cw2[2], cb2[2], pooled);

    vae_pooldec<<<BG, 256, 0, stream>>>(pooled, stats, bng, bnb, fcw, fcb, muw, mub, d0w, d0b, d1w, d1b, Dm);

    // d2 head: diff-GEMM (d2w + gum read raw, diffs inline) -> vals, scatter to adjacency
    vae_d2gemm<<<dim3(8192 / 64, BG / 128), 256, 0, stream>>>(Dm, d2w, d2b, gum, vals);
    vae_scatter<<<BG, 256, 0, stream>>>(vals, Out);
}

// Round 15
// 926.913 us; speedup vs baseline: 1.0352x; 1.0352x over previous
//
#include <hip/hip_runtime.h>

#define NN 65536
#define NE 524288
#define BG 512
#define DIN 128
#define HE 256
#define LATD 64
#define HD 512
#define NMX 128
#define NPAIR 8128
#define NST 7

// ---------------- CSR build ----------------
__global__ void vae_hist(const int* __restrict__ dst, int* __restrict__ cnt) {
    int e = blockIdx.x * 256 + threadIdx.x;
    if (e < NE) atomicAdd(&cnt[dst[e]], 1);
}

// two-level scan
__global__ void vae_scan1(const int* __restrict__ cnt, int* __restrict__ excl, int* __restrict__ bsum) {
    __shared__ int sd[256];
    const int b = blockIdx.x, t = threadIdx.x;
    int v = cnt[b * 256 + t];
    sd[t] = v;
    __syncthreads();
    int acc = v;
    for (int off = 1; off < 256; off <<= 1) {
        int tv = (t >= off) ? sd[t - off] : 0;
        __syncthreads();
        acc += tv;
        sd[t] = acc;
        __syncthreads();
    }
    excl[b * 256 + t] = acc - v;
    if (t == 255) bsum[b] = acc;
}

__global__ void vae_scan2(int* __restrict__ bsum) {
    __shared__ int sd[256];
    const int t = threadIdx.x;
    int v = bsum[t];
    sd[t] = v;
    __syncthreads();
    int acc = v;
    for (int off = 1; off < 256; off <<= 1) {
        int tv = (t >= off) ? sd[t - off] : 0;
        __syncthreads();
        acc += tv;
        sd[t] = acc;
        __syncthreads();
    }
    bsum[t] = acc - v;  // exclusive
}

__global__ void vae_scan3(const int* __restrict__ excl, const int* __restrict__ bsum,
                          int* __restrict__ rs, int* __restrict__ cur) {
    const int i = blockIdx.x * 256 + threadIdx.x;
    const int v = excl[i] + bsum[blockIdx.x];
    rs[i] = v;
    cur[i] = v;
    if (i == NN - 1) rs[NN] = NE;
}

__global__ void vae_fill(const int* __restrict__ dst, int* __restrict__ cur, int* __restrict__ eid) {
    int e = blockIdx.x * 256 + threadIdx.x;
    if (e < NE) {
        int p = atomicAdd(&cur[dst[e]], 1);
        eid[p] = e;
    }
}

// canonicalize order (deterministic)
__global__ void vae_sort(const int* __restrict__ rs, int* __restrict__ eid,
                         const int* __restrict__ srcarr, int* __restrict__ csrc) {
    int n = blockIdx.x * 256 + threadIdx.x;
    if (n >= NN) return;
    int s = rs[n], e = rs[n + 1];
    for (int a = s + 1; a < e; ++a) {
        int key = eid[a];
        int b = a - 1;
        while (b >= s && eid[b] > key) { eid[b + 1] = eid[b]; --b; }
        eid[b + 1] = key;
    }
    for (int a = s; a < e; ++a) csrc[a] = srcarr[eid[a]];
}

// ---------------- fused agg + GEMM1: T = bn(lrelu((h + gather) @ W1 + b1)) -------------------
// 128x256 / BK=32 proven structure; A-staging gathers h[row] + sum h[csrc[a]].
// Gather issues loads 5 edges at a time (+2-wide and 1-wide tails) BUT accumulates strictly
// IN EDGE ORDER into a single chain — bitwise-identical to the sequential CSR walk.
// NUMERICS RULE (round-10 failure): the edge-sum ORDER is load-bearing; only load scheduling
// may be parallelized, never the adds.
// MEASURED OPTIMUM (round 12, 930 us): csrc-LDS staging (r13) and 4-wide split chains (r10)
// both regressed/failed — do not revisit.
template <int K>
__global__ __launch_bounds__(256, 2) void vae_gemm1f(const float* __restrict__ Hm,
                                                     const int* __restrict__ rs,
                                                     const int* __restrict__ csrc,
                                                     const float* __restrict__ W,
                                                     const float* __restrict__ bias,
                                                     const float* __restrict__ g,
                                                     const float* __restrict__ be,
                                                     float* __restrict__ Out) {
    __shared__ float As[32][132];
    __shared__ float Bs[32][264];
    const int tid = threadIdx.x;
    const int tx = tid & 15, ty = tid >> 4;
    const int rowBlk = blockIdx.x * 128;

    float acc[8][16];
#pragma unroll
    for (int r = 0; r < 8; r++)
#pragma unroll
        for (int c = 0; c < 16; c++) acc[r][c] = 0.f;

    const int arow = tid >> 1;       // 0..127
    const int ak = (tid & 1) * 16;   // 0 or 16
    const int row = rowBlk + arow;
    const int s0 = rs[row], e0 = rs[row + 1];
    const float* aown = Hm + (size_t)row * K + ak;
    const float* bptr = W + (size_t)ty * HE + tx * 4;  // stages k-rows ty and ty+16

    float4 pa0, pa1, pa2, pa3;
    float4 pb0, pb1, pb2, pb3, pb4, pb5, pb6, pb7;
    auto gload = [&](int ck) {
        const size_t off = (size_t)ak + (size_t)ck * 32;
        const float* an = aown + ck * 32;
        pa0 = *reinterpret_cast<const float4*>(an);
        pa1 = *reinterpret_cast<const float4*>(an + 4);
        pa2 = *reinterpret_cast<const float4*>(an + 8);
        pa3 = *reinterpret_cast<const float4*>(an + 12);
        int a = s0;
        // 5-edge load batches; IN-ORDER single-chain accumulation (matches reference).
        while (a + 4 < e0) {
            const float* p0 = Hm + (size_t)csrc[a] * K + off;
            const float* p1 = Hm + (size_t)csrc[a + 1] * K + off;
            const float* p2 = Hm + (size_t)csrc[a + 2] * K + off;
            const float* p3 = Hm + (size_t)csrc[a + 3] * K + off;
            const float* p4 = Hm + (size_t)csrc[a + 4] * K + off;
            float4 n0 = *reinterpret_cast<const float4*>(p0);
            float4 n1 = *reinterpret_cast<const float4*>(p0 + 4);
            float4 n2 = *reinterpret_cast<const float4*>(p0 + 8);
            float4 n3 = *reinterpret_cast<const float4*>(p0 + 12);
            float4 m0 = *reinterpret_cast<const float4*>(p1);
            float4 m1 = *reinterpret_cast<const float4*>(p1 + 4);
            float4 m2 = *reinterpret_cast<const float4*>(p1 + 8);
            float4 m3 = *reinterpret_cast<const float4*>(p1 + 12);
            float4 u0 = *reinterpret_cast<const float4*>(p2);
            float4 u1 = *reinterpret_cast<const float4*>(p2 + 4);
            float4 u2 = *reinterpret_cast<const float4*>(p2 + 8);
            float4 u3 = *reinterpret_cast<const float4*>(p2 + 12);
            float4 v0 = *reinterpret_cast<const float4*>(p3);
            float4 v1 = *reinterpret_cast<const float4*>(p3 + 4);
            float4 v2 = *reinterpret_cast<const float4*>(p3 + 8);
            float4 v3 = *reinterpret_cast<const float4*>(p3 + 12);
            float4 w0 = *reinterpret_cast<const float4*>(p4);
            float4 w1 = *reinterpret_cast<const float4*>(p4 + 4);
            float4 w2 = *reinterpret_cast<const float4*>(p4 + 8);
            float4 w3 = *reinterpret_cast<const float4*>(p4 + 12);
            // edge a
            pa0.x += n0.x; pa0.y += n0.y; pa0.z += n0.z; pa0.w += n0.w;
            pa1.x += n1.x; pa1.y += n1.y; pa1.z += n1.z; pa1.w += n1.w;
            pa2.x += n2.x; pa2.y += n2.y; pa2.z += n2.z; pa2.w += n2.w;
            pa3.x += n3.x; pa3.y += n3.y; pa3.z += n3.z; pa3.w += n3.w;
            // edge a+1
            pa0.x += m0.x; pa0.y += m0.y; pa0.z += m0.z; pa0.w += m0.w;
            pa1.x += m1.x; pa1.y += m1.y; pa1.z += m1.z; pa1.w += m1.w;
            pa2.x += m2.x; pa2.y += m2.y; pa2.z += m2.z; pa2.w += m2.w;
            pa3.x += m3.x; pa3.y += m3.y; pa3.z += m3.z; pa3.w += m3.w;
            // edge a+2
            pa0.x += u0.x; pa0.y += u0.y; pa0.z += u0.z; pa0.w += u0.w;
            pa1.x += u1.x; pa1.y += u1.y; pa1.z += u1.z; pa1.w += u1.w;
            pa2.x += u2.x; pa2.y += u2.y; pa2.z += u2.z; pa2.w += u2.w;
            pa3.x += u3.x; pa3.y += u3.y; pa3.z += u3.z; pa3.w += u3.w;
            // edge a+3
            pa0.x += v0.x; pa0.y += v0.y; pa0.z += v0.z; pa0.w += v0.w;
            pa1.x += v1.x; pa1.y += v1.y; pa1.z += v1.z; pa1.w += v1.w;
            pa2.x += v2.x; pa2.y += v2.y; pa2.z += v2.z; pa2.w += v2.w;
            pa3.x += v3.x; pa3.y += v3.y; pa3.z += v3.z; pa3.w += v3.w;
            // edge a+4
            pa0.x += w0.x; pa0.y += w0.y; pa0.z += w0.z; pa0.w += w0.w;
            pa1.x += w1.x; pa1.y += w1.y; pa1.z += w1.z; pa1.w += w1.w;
            pa2.x += w2.x; pa2.y += w2.y; pa2.z += w2.z; pa2.w += w2.w;
            pa3.x += w3.x; pa3.y += w3.y; pa3.z += w3.z; pa3.w += w3.w;
            a += 5;
        }
        // 2-edge tail batches
        while (a + 1 < e0) {
            const float* p0 = Hm + (size_t)csrc[a] * K + off;
            const float* p1 = Hm + (size_t)csrc[a + 1] * K + off;
            float4 n0 = *reinterpret_cast<const float4*>(p0);
            float4 n1 = *reinterpret_cast<const float4*>(p0 + 4);
            float4 n2 = *reinterpret_cast<const float4*>(p0 + 8);
            float4 n3 = *reinterpret_cast<const float4*>(p0 + 12);
            float4 m0 = *reinterpret_cast<const float4*>(p1);
            float4 m1 = *reinterpret_cast<const float4*>(p1 + 4);
            float4 m2 = *reinterpret_cast<const float4*>(p1 + 8);
            float4 m3 = *reinterpret_cast<const float4*>(p1 + 12);
            pa0.x += n0.x; pa0.y += n0.y; pa0.z += n0.z; pa0.w += n0.w;
            pa1.x += n1.x; pa1.y += n1.y; pa1.z += n1.z; pa1.w += n1.w;
            pa2.x += n2.x; pa2.y += n2.y; pa2.z += n2.z; pa2.w += n2.w;
            pa3.x += n3.x; pa3.y += n3.y; pa3.z += n3.z; pa3.w += n3.w;
            pa0.x += m0.x; pa0.y += m0.y; pa0.z += m0.z; pa0.w += m0.w;
            pa1.x += m1.x; pa1.y += m1.y; pa1.z += m1.z; pa1.w += m1.w;
            pa2.x += m2.x; pa2.y += m2.y; pa2.z += m2.z; pa2.w += m2.w;
            pa3.x += m3.x; pa3.y += m3.y; pa3.z += m3.z; pa3.w += m3.w;
            a += 2;
        }
        if (a < e0) {
            const float* p0 = Hm + (size_t)csrc[a] * K + off;
            float4 n0 = *reinterpret_cast<const float4*>(p0);
            float4 n1 = *reinterpret_cast<const float4*>(p0 + 4);
            float4 n2 = *reinterpret_cast<const float4*>(p0 + 8);
            float4 n3 = *reinterpret_cast<const float4*>(p0 + 12);
            pa0.x += n0.x; pa0.y += n0.y; pa0.z += n0.z; pa0.w += n0.w;
            pa1.x += n1.x; pa1.y += n1.y; pa1.z += n1.z; pa1.w += n1.w;
            pa2.x += n2.x; pa2.y += n2.y; pa2.z += n2.z; pa2.w += n2.w;
            pa3.x += n3.x; pa3.y += n3.y; pa3.z += n3.z; pa3.w += n3.w;
        }
        // B-panel loads last: consumed at next swrite, covered by the FMA loop.
        const float* bn0 = bptr + (size_t)(ck * 32) * HE;
        pb0 = *reinterpret_cast<const float4*>(bn0);
        pb1 = *reinterpret_cast<const float4*>(bn0 + 64);
        pb2 = *reinterpret_cast<const float4*>(bn0 + 128);
        pb3 = *reinterpret_cast<const float4*>(bn0 + 192);
        const float* bn1 = bn0 + 16 * HE;
        pb4 = *reinterpret_cast<const float4*>(bn1);
        pb5 = *reinterpret_cast<const float4*>(bn1 + 64);
        pb6 = *reinterpret_cast<const float4*>(bn1 + 128);
        pb7 = *reinterpret_cast<const float4*>(bn1 + 192);
    };
    auto swrite = [&]() {
        As[ak + 0][arow] = pa0.x;  As[ak + 1][arow] = pa0.y;
        As[ak + 2][arow] = pa0.z;  As[ak + 3][arow] = pa0.w;
        As[ak + 4][arow] = pa1.x;  As[ak + 5][arow] = pa1.y;
        As[ak + 6][arow] = pa1.z;  As[ak + 7][arow] = pa1.w;
        As[ak + 8][arow] = pa2.x;  As[ak + 9][arow] = pa2.y;
        As[ak + 10][arow] = pa2.z; As[ak + 11][arow] = pa2.w;
        As[ak + 12][arow] = pa3.x; As[ak + 13][arow] = pa3.y;
        As[ak + 14][arow] = pa3.z; As[ak + 15][arow] = pa3.w;
        *reinterpret_cast<float4*>(&Bs[ty][tx * 4]) = pb0;
        *reinterpret_cast<float4*>(&Bs[ty][tx * 4 + 64]) = pb1;
        *reinterpret_cast<float4*>(&Bs[ty][tx * 4 + 128]) = pb2;
        *reinterpret_cast<float4*>(&Bs[ty][tx * 4 + 192]) = pb3;
        *reinterpret_cast<float4*>(&Bs[ty + 16][tx * 4]) = pb4;
        *reinterpret_cast<float4*>(&Bs[ty + 16][tx * 4 + 64]) = pb5;
        *reinterpret_cast<float4*>(&Bs[ty + 16][tx * 4 + 128]) = pb6;
        *reinterpret_cast<float4*>(&Bs[ty + 16][tx * 4 + 192]) = pb7;
    };

    constexpr int NCK = K / 32;
    gload(0);
    for (int ck = 0; ck < NCK; ++ck) {
        __syncthreads();
        swrite();
        __syncthreads();
        if (ck + 1 < NCK) gload(ck + 1);
#pragma unroll 16
        for (int k = 0; k < 32; ++k) {
            float4 a0 = *reinterpret_cast<const float4*>(&As[k][ty * 8]);
            float4 a1 = *reinterpret_cast<const float4*>(&As[k][ty * 8 + 4]);
            float4 b0 = *reinterpret_cast<const float4*>(&Bs[k][tx * 4]);
            float4 b1 = *reinterpret_cast<const float4*>(&Bs[k][tx * 4 + 64]);
            float4 b2 = *reinterpret_cast<const float4*>(&Bs[k][tx * 4 + 128]);
            float4 b3 = *reinterpret_cast<const float4*>(&Bs[k][tx * 4 + 192]);
            float ar[8] = {a0.x, a0.y, a0.z, a0.w, a1.x, a1.y, a1.z, a1.w};
            float bv[16] = {b0.x, b0.y, b0.z, b0.w, b1.x, b1.y, b1.z, b1.w,
                            b2.x, b2.y, b2.z, b2.w, b3.x, b3.y, b3.z, b3.w};
#pragma unroll
            for (int r = 0; r < 8; r++)
#pragma unroll
                for (int c = 0; c < 16; c++)
                    acc[r][c] = fmaf(ar[r], bv[c], acc[r][c]);
        }
    }

    const float sq = sqrtf(1.0f + 1e-5f);
#pragma unroll
    for (int cg = 0; cg < 4; cg++) {
        const int col = cg * 64 + tx * 4;
        float4 bb = *reinterpret_cast<const float4*>(&bias[col]);
        float4 gg = *reinterpret_cast<const float4*>(&g[col]);
        float4 ee = *reinterpret_cast<const float4*>(&be[col]);
        float bbv[4] = {bb.x, bb.y, bb.z, bb.w};
        float sc[4] = {gg.x / sq, gg.y / sq, gg.z / sq, gg.w / sq};
        float bev[4] = {ee.x, ee.y, ee.z, ee.w};
#pragma unroll
        for (int r = 0; r < 8; r++) {
            const int orow = rowBlk + ty * 8 + r;
            float o[4];
#pragma unroll
            for (int c = 0; c < 4; c++) {
                float t = acc[r][cg * 4 + c] + bbv[c];
                t = t > 0.f ? t : 0.2f * t;
                o[c] = t * sc[c] + bev[c];
            }
            *reinterpret_cast<float4*>(Out + (size_t)orow * HE + col) =
                *reinterpret_cast<float4*>(&o[0]);
        }
    }
}

// ---------------- LDS-staged SGEMM (gemm2), 128x256, BK=32, proven operating point -----------
// EPI 1: lrelu(.) -> Out; EPI 2: lrelu(.) -> per-graph pooled column sums (NO h store)
template <int K, int EPI>
__global__ __launch_bounds__(256, 2) void vae_sgemm(const float* __restrict__ A,
                                                    const float* __restrict__ W,
                                                    const float* __restrict__ bias,
                                                    float* __restrict__ Out) {
    __shared__ float As[32][132];
    __shared__ float Bs[32][264];
    const int tid = threadIdx.x;
    const int tx = tid & 15, ty = tid >> 4;
    const int rowBlk = blockIdx.x * 128;

    float acc[8][16];
#pragma unroll
    for (int r = 0; r < 8; r++)
#pragma unroll
        for (int c = 0; c < 16; c++) acc[r][c] = 0.f;

    const int arow = tid >> 1;       // 0..127
    const int ak = (tid & 1) * 16;   // 0 or 16
    const float* aptr = A + (size_t)(rowBlk + arow) * K + ak;
    const float* bptr = W + (size_t)ty * HE + tx * 4;  // stages k-rows ty and ty+16

    float4 pa0, pa1, pa2, pa3;
    float4 pb0, pb1, pb2, pb3, pb4, pb5, pb6, pb7;
    auto gload = [&](int ck) {
        const float* an = aptr + ck * 32;
        pa0 = *reinterpret_cast<const float4*>(an);
        pa1 = *reinterpret_cast<const float4*>(an + 4);
        pa2 = *reinterpret_cast<const float4*>(an + 8);
        pa3 = *reinterpret_cast<const float4*>(an + 12);
        const float* bn0 = bptr + (size_t)(ck * 32) * HE;
        pb0 = *reinterpret_cast<const float4*>(bn0);
        pb1 = *reinterpret_cast<const float4*>(bn0 + 64);
        pb2 = *reinterpret_cast<const float4*>(bn0 + 128);
        pb3 = *reinterpret_cast<const float4*>(bn0 + 192);
        const float* bn1 = bn0 + 16 * HE;
        pb4 = *reinterpret_cast<const float4*>(bn1);
        pb5 = *reinterpret_cast<const float4*>(bn1 + 64);
        pb6 = *reinterpret_cast<const float4*>(bn1 + 128);
        pb7 = *reinterpret_cast<const float4*>(bn1 + 192);
    };
    auto swrite = [&]() {
        As[ak + 0][arow] = pa0.x;  As[ak + 1][arow] = pa0.y;
        As[ak + 2][arow] = pa0.z;  As[ak + 3][arow] = pa0.w;
        As[ak + 4][arow] = pa1.x;  As[ak + 5][arow] = pa1.y;
        As[ak + 6][arow] = pa1.z;  As[ak + 7][arow] = pa1.w;
        As[ak + 8][arow] = pa2.x;  As[ak + 9][arow] = pa2.y;
        As[ak + 10][arow] = pa2.z; As[ak + 11][arow] = pa2.w;
        As[ak + 12][arow] = pa3.x; As[ak + 13][arow] = pa3.y;
        As[ak + 14][arow] = pa3.z; As[ak + 15][arow] = pa3.w;
        *reinterpret_cast<float4*>(&Bs[ty][tx * 4]) = pb0;
        *reinterpret_cast<float4*>(&Bs[ty][tx * 4 + 64]) = pb1;
        *reinterpret_cast<float4*>(&Bs[ty][tx * 4 + 128]) = pb2;
        *reinterpret_cast<float4*>(&Bs[ty][tx * 4 + 192]) = pb3;
        *reinterpret_cast<float4*>(&Bs[ty + 16][tx * 4]) = pb4;
        *reinterpret_cast<float4*>(&Bs[ty + 16][tx * 4 + 64]) = pb5;
        *reinterpret_cast<float4*>(&Bs[ty + 16][tx * 4 + 128]) = pb6;
        *reinterpret_cast<float4*>(&Bs[ty + 16][tx * 4 + 192]) = pb7;
    };

    constexpr int NCK = K / 32;
    gload(0);
    for (int ck = 0; ck < NCK; ++ck) {
        __syncthreads();
        swrite();
        __syncthreads();
        if (ck + 1 < NCK) gload(ck + 1);
#pragma unroll 16
        for (int k = 0; k < 32; ++k) {
            float4 a0 = *reinterpret_cast<const float4*>(&As[k][ty * 8]);
            float4 a1 = *reinterpret_cast<const float4*>(&As[k][ty * 8 + 4]);
            float4 b0 = *reinterpret_cast<const float4*>(&Bs[k][tx * 4]);
            float4 b1 = *reinterpret_cast<const float4*>(&Bs[k][tx * 4 + 64]);
            float4 b2 = *reinterpret_cast<const float4*>(&Bs[k][tx * 4 + 128]);
            float4 b3 = *reinterpret_cast<const float4*>(&Bs[k][tx * 4 + 192]);
            float ar[8] = {a0.x, a0.y, a0.z, a0.w, a1.x, a1.y, a1.z, a1.w};
            float bv[16] = {b0.x, b0.y, b0.z, b0.w, b1.x, b1.y, b1.z, b1.w,
                            b2.x, b2.y, b2.z, b2.w, b3.x, b3.y, b3.z, b3.w};
#pragma unroll
            for (int r = 0; r < 8; r++)
#pragma unroll
                for (int c = 0; c < 16; c++)
                    acc[r][c] = fmaf(ar[r], bv[c], acc[r][c]);
        }
    }

    if constexpr (EPI == 2) {
        float psum[16];
#pragma unroll
        for (int c = 0; c < 16; c++) psum[c] = 0.f;
#pragma unroll
        for (int cg = 0; cg < 4; cg++) {
            const int col = cg * 64 + tx * 4;
            float4 bb = *reinterpret_cast<const float4*>(&bias[col]);
            float bbv[4] = {bb.x, bb.y, bb.z, bb.w};
#pragma unroll
            for (int r = 0; r < 8; r++)
#pragma unroll
                for (int c = 0; c < 4; c++) {
                    float t = acc[r][cg * 4 + c] + bbv[c];
                    t = t > 0.f ? t : 0.2f * t;
                    psum[cg * 4 + c] += t;
                }
        }
        __syncthreads();
#pragma unroll
        for (int cg = 0; cg < 4; cg++)
#pragma unroll
            for (int c = 0; c < 4; c++)
                Bs[ty][cg * 64 + tx * 4 + c] = psum[cg * 4 + c];
        __syncthreads();
        float s = 0.f;
#pragma unroll
        for (int k = 0; k < 16; k++) s += Bs[k][tid];
        Out[(size_t)blockIdx.x * HE + tid] = s;  // pooled[graph][col]
        return;
    }

#pragma unroll
    for (int cg = 0; cg < 4; cg++) {
        const int col = cg * 64 + tx * 4;
        float4 bb = *reinterpret_cast<const float4*>(&bias[col]);
        float bbv[4] = {bb.x, bb.y, bb.z, bb.w};
#pragma unroll
        for (int r = 0; r < 8; r++) {
            const int row = rowBlk + ty * 8 + r;
            float o[4];
#pragma unroll
            for (int c = 0; c < 4; c++) {
                float t = acc[r][cg * 4 + c] + bbv[c];
                o[c] = t > 0.f ? t : 0.2f * t;
            }
            *reinterpret_cast<float4*>(Out + (size_t)row * HE + col) =
                *reinterpret_cast<float4*>(&o[0]);
        }
    }
}

// ---------------- pooled(precomputed) -> bn -> fc -> mu -> d0 -> d1, one block per graph ----
__global__ __launch_bounds__(256) void vae_pooldec(const float* __restrict__ pooled, const float* __restrict__ stats,
                                                   const float* __restrict__ bng, const float* __restrict__ bnb,
                                                   const float* __restrict__ fcw, const float* __restrict__ fcb,
                                                   const float* __restrict__ muw, const float* __restrict__ mub,
                                                   const float* __restrict__ d0w, const float* __restrict__ d0b,
                                                   const float* __restrict__ d1w, const float* __restrict__ d1b,
                                                   float* __restrict__ Dm) {
    __shared__ float vin[264];
    __shared__ float fo[256];
    __shared__ float z[72];
    __shared__ float dd[512];
    const int b = blockIdx.x, t = threadIdx.x;

    const float sq = sqrtf(1.0f + 1e-5f);
    float m0 = pooled[(size_t)b * HE + t] * (bng[t] / sq) + bnb[t];
    vin[t] = m0;
    if (t < NST) vin[HE + t] = stats[b * NST + t] * (bng[HE + t] / sq) + bnb[HE + t];
    __syncthreads();

    float a = fcb[t];
    for (int k = 0; k < HE + NST; k++) a = fmaf(vin[k], fcw[(size_t)k * HE + t], a);
    fo[t] = a;
    __syncthreads();

    if (t < LATD) {
        float m = mub[t];
        for (int k = 0; k < HE; k++) m = fmaf(fo[k], muw[(size_t)k * LATD + t], m);
        z[t] = m;
    }
    if (t >= LATD && t < LATD + NST) z[t] = stats[b * NST + (t - LATD)];
    __syncthreads();

    float a0 = d0b[t], a1 = d0b[t + 256];
    for (int k = 0; k < LATD + NST; k++) {
        float zk = z[k];
        a0 = fmaf(zk, d0w[(size_t)k * HD + t], a0);
        a1 = fmaf(zk, d0w[(size_t)k * HD + t + 256], a1);
    }
    dd[t] = a0 > 0.f ? a0 : 0.f;
    dd[t + 256] = a1 > 0.f ? a1 : 0.f;
    __syncthreads();

    float c0 = d1b[t], c1 = d1b[t + 256];
    for (int k = 0; k < HD; k++) {
        float dk = dd[k];
        c0 = fmaf(dk, d1w[(size_t)k * HD + t], c0);
        c1 = fmaf(dk, d1w[(size_t)k * HD + t + 256], c1);
    }
    Dm[(size_t)b * HD + t] = c0 > 0.f ? c0 : 0.f;
    Dm[(size_t)b * HD + t + 256] = c1 > 0.f ? c1 : 0.f;
}

// ---------------- d2 difference-GEMM, 128 rows x 64 cols, grid (128,4)=512 blocks ------------
// B-staging reads RAW d2w pairs and diffs inline; epilogue reads gum directly and writes vals.
__global__ __launch_bounds__(256, 4) void vae_d2gemm(const float* __restrict__ A,    // Dm 512x512
                                                     const float* __restrict__ Wraw, // d2w 512x16256
                                                     const float* __restrict__ Bb,   // d2b 16256
                                                     const float* __restrict__ gum,  // 512x16256
                                                     float* __restrict__ Vals) {     // 512x8192
    __shared__ float As[16][132];
    __shared__ float Bs[16][68];
    const int tid = threadIdx.x;
    const int tx = tid & 15, ty = tid >> 4;
    const int rowBlk = blockIdx.y * 128, colBlk = blockIdx.x * 64;

    float acc[8][4];
#pragma unroll
    for (int r = 0; r < 8; r++)
#pragma unroll
        for (int c = 0; c < 4; c++) acc[r][c] = 0.f;

    const int arow = tid >> 1;
    const int ak = (tid & 1) * 8;
    const float* aptr = A + (size_t)(rowBlk + arow) * HD + ak;
    const int bk = tid >> 4;        // 0..15 (k row within chunk)
    const int bc = (tid & 15) * 4;  // 0..60 (pair group)
    const int p0 = colBlk + bc;     // pair index, multiple of 4
    const bool pvalid = (p0 < NPAIR);  // NPAIR % 4 == 0, so all 4 pairs valid together
    const float* wrow = Wraw + (size_t)bk * (2 * NPAIR) + 2 * p0;

    float4 pa0 = *reinterpret_cast<const float4*>(aptr);
    float4 pa1 = *reinterpret_cast<const float4*>(aptr + 4);
    float4 pu = {0.f, 0.f, 0.f, 0.f}, pv = {0.f, 0.f, 0.f, 0.f};
    if (pvalid) {
        pu = *reinterpret_cast<const float4*>(wrow);
        pv = *reinterpret_cast<const float4*>(wrow + 4);
    }

    constexpr int NCK = HD / 16;
    for (int ck = 0; ck < NCK; ++ck) {
        __syncthreads();
        As[ak + 0][arow] = pa0.x;
        As[ak + 1][arow] = pa0.y;
        As[ak + 2][arow] = pa0.z;
        As[ak + 3][arow] = pa0.w;
        As[ak + 4][arow] = pa1.x;
        As[ak + 5][arow] = pa1.y;
        As[ak + 6][arow] = pa1.z;
        As[ak + 7][arow] = pa1.w;
        {
            float4 d;
            d.x = pu.x - pu.y; d.y = pu.z - pu.w;
            d.z = pv.x - pv.y; d.w = pv.z - pv.w;
            *reinterpret_cast<float4*>(&Bs[bk][bc]) = d;
        }
        __syncthreads();
        if (ck + 1 < NCK) {
            const float* an = aptr + (ck + 1) * 16;
            pa0 = *reinterpret_cast<const float4*>(an);
            pa1 = *reinterpret_cast<const float4*>(an + 4);
            if (pvalid) {
                const float* wn = wrow + (size_t)(ck + 1) * 16 * (2 * NPAIR);
                pu = *reinterpret_cast<const float4*>(wn);
                pv = *reinterpret_cast<const float4*>(wn + 4);
            }
        }
#pragma unroll
        for (int k = 0; k < 16; ++k) {
            float4 a0 = *reinterpret_cast<const float4*>(&As[k][ty * 8]);
            float4 a1 = *reinterpret_cast<const float4*>(&As[k][ty * 8 + 4]);
            float4 b = *reinterpret_cast<const float4*>(&Bs[k][tx * 4]);
            float ar[8] = {a0.x, a0.y, a0.z, a0.w, a1.x, a1.y, a1.z, a1.w};
            float bv[4] = {b.x, b.y, b.z, b.w};
#pragma unroll
            for (int r = 0; r < 8; r++)
#pragma unroll
                for (int c = 0; c < 4; c++)
                    acc[r][c] = fmaf(ar[r], bv[c], acc[r][c]);
        }
    }

    if (pvalid) {
        const float* bp = Bb + 2 * p0;
        float4 u = *reinterpret_cast<const float4*>(bp);
        float4 v = *reinterpret_cast<const float4*>(bp + 4);
        float bd[4] = {u.x - u.y, u.z - u.w, v.x - v.y, v.z - v.w};
#pragma unroll
        for (int r = 0; r < 8; r++) {
            const int b_ = rowBlk + ty * 8 + r;
            const float* gp = gum + (size_t)b_ * (2 * NPAIR) + 2 * p0;
            float4 gu = *reinterpret_cast<const float4*>(gp);
            float4 gv = *reinterpret_cast<const float4*>(gp + 4);
            float gd[4] = {gu.x - gu.y, gu.z - gu.w, gv.x - gv.y, gv.z - gv.w};
            float o[4];
#pragma unroll
            for (int c = 0; c < 4; c++) {
                float y = acc[r][c] + bd[c] + gd[c];
                o[c] = (y >= 0.f) ? 1.0f : 0.0f;
            }
            *reinterpret_cast<float4*>(Vals + (size_t)b_ * 8192 + p0) =
                *reinterpret_cast<float4*>(&o[0]);
        }
    }
}

// ---------------- scatter: vals -> symmetric adjacency, one block per graph ----------------
__global__ __launch_bounds__(256) void vae_scatter(const float* __restrict__ vals, float* __restrict__ Out) {
    __shared__ float sv[8192];
    const int b = blockIdx.x, t = threadIdx.x;
    const float* vp = vals + (size_t)b * 8192;
#pragma unroll
    for (int i = 0; i < 8; ++i)
        *reinterpret_cast<float4*>(&sv[(i * 256 + t) * 4]) =
            *reinterpret_cast<const float4*>(&vp[(i * 256 + t) * 4]);
    __syncthreads();
    float* op = Out + (size_t)b * (NMX * NMX);
#pragma unroll
    for (int it = 0; it < 16; ++it) {
        int pos = (it * 256 + t) * 4;
        int i = pos >> 7, j0 = pos & 127;
        float o[4];
#pragma unroll
        for (int e = 0; e < 4; ++e) {
            int j = j0 + e;
            float v;
            if (i == j) v = 0.f;
            else if (i < j) v = sv[((i * (255 - i)) >> 1) + j - i - 1];
            else v = sv[((j * (255 - j)) >> 1) + i - j - 1];
            o[e] = v;
        }
        *reinterpret_cast<float4*>(&op[pos]) = *reinterpret_cast<float4*>(&o[0]);
    }
}

extern "C" void kernel_launch(void* const* d_in, const int* in_sizes, int n_in,
                              void* d_out, int out_size, void* d_ws, size_t ws_size,
                              hipStream_t stream) {
    const float* x = (const float*)d_in[0];
    const int* ei = (const int*)d_in[1];  // [0..NE) = src, [NE..2NE) = dst
    const float* stats = (const float*)d_in[3];
    const float* gum = (const float*)d_in[4];
    const float* cw1[3] = {(const float*)d_in[5], (const float*)d_in[11], (const float*)d_in[17]};
    const float* cb1[3] = {(const float*)d_in[6], (const float*)d_in[12], (const float*)d_in[18]};
    const float* cg[3] = {(const float*)d_in[7], (const float*)d_in[13], (const float*)d_in[19]};
    const float* cbe[3] = {(const float*)d_in[8], (const float*)d_in[14], (const float*)d_in[20]};
    const float* cw2[3] = {(const float*)d_in[9], (const float*)d_in[15], (const float*)d_in[21]};
    const float* cb2[3] = {(const float*)d_in[10], (const float*)d_in[16], (const float*)d_in[22]};
    const float* bng = (const float*)d_in[23];
    const float* bnb = (const float*)d_in[24];
    const float* fcw = (const float*)d_in[25];
    const float* fcb = (const float*)d_in[26];
    const float* muw = (const float*)d_in[27];
    const float* mub = (const float*)d_in[28];
    const float* d0w = (const float*)d_in[29];
    const float* d0b = (const float*)d_in[30];
    const float* d1w = (const float*)d_in[31];
    const float* d1b = (const float*)d_in[32];
    const float* d2w = (const float*)d_in[33];
    const float* d2b = (const float*)d_in[34];
    float* Out = (float*)d_out;

    char* wp = (char*)d_ws;
    auto alloc = [&](size_t bytes) -> void* {
        void* p = (void*)wp;
        wp += (bytes + 255) & ~(size_t)255;
        return p;
    };
    float* hA = (float*)alloc((size_t)NN * HE * 4);
    float* hB = (float*)alloc((size_t)NN * HE * 4);
    int* cnt = (int*)alloc((size_t)NN * 4);
    int* rs = (int*)alloc((size_t)(NN + 64) * 4);
    int* cur = (int*)alloc((size_t)NN * 4);
    int* eid = (int*)alloc((size_t)NE * 4);
    int* csrc = (int*)alloc((size_t)NE * 4);
    int* bsum = (int*)alloc((size_t)256 * 4);
    float* Dm = (float*)alloc((size_t)BG * HD * 4);
    float* pooled = (float*)alloc((size_t)BG * HE * 4);

    // vals aliases hA: hA is dead after the last gemm2 reads it, and the d2 chain
    // launches after that point (stream-ordered).
    float* vals = hA;  // 512 x 8192

    const int* srcArr = ei;
    const int* dstArr = ei + NE;

    hipMemsetAsync(cnt, 0, (size_t)NN * 4, stream);
    vae_hist<<<NE / 256, 256, 0, stream>>>(dstArr, cnt);
    vae_scan1<<<NN / 256, 256, 0, stream>>>(cnt, cur, bsum);
    vae_scan2<<<1, 256, 0, stream>>>(bsum);
    vae_scan3<<<NN / 256, 256, 0, stream>>>(cur, bsum, rs, cur);
    vae_fill<<<NE / 256, 256, 0, stream>>>(dstArr, cur, eid);
    vae_sort<<<NN / 256, 256, 0, stream>>>(rs, eid, srcArr, csrc);

    // layer 0: fused agg+gemm1: x -> hA(T); gemm2: hA -> hB(h1)
    vae_gemm1f<DIN><<<NN / 128, 256, 0, stream>>>(x, rs, csrc, cw1[0], cb1[0], cg[0], cbe[0], hA);
    vae_sgemm<HE, 1><<<NN / 128, 256, 0, stream>>>(hA, cw2[0], cb2[0], hB);
    // layer 1
    vae_gemm1f<HE><<<NN / 128, 256, 0, stream>>>(hB, rs, csrc, cw1[1], cb1[1], cg[1], cbe[1], hA);
    vae_sgemm<HE, 1><<<NN / 128, 256, 0, stream>>>(hA, cw2[1], cb2[1], hB);
    // layer 2: fused agg+gemm1: hB -> hA(T3); gemm2(EPI=2): hA -> pooled (no h store)
    vae_gemm1f<HE><<<NN / 128, 256, 0, stream>>>(hB, rs, csrc, cw1[2], cb1[2], cg[2], cbe[2], hA);
    vae_sgemm<HE, 2><<<NN / 128, 256, 0, stream>>>(hA, cw2[2], cb2[2], pooled);

    vae_pooldec<<<BG, 256, 0, stream>>>(pooled, stats, bng, bnb, fcw, fcb, muw, mub, d0w, d0b, d1w, d1b, Dm);

    // d2 head: diff-GEMM (d2w + gum read raw, diffs inline) -> vals, scatter to adjacency
    vae_d2gemm<<<dim3(8192 / 64, BG / 128), 256, 0, stream>>>(Dm, d2w, d2b, gum, vals);
    vae_scatter<<<BG, 256, 0, stream>>>(vals, Out);
}